// Round 6
// baseline (781.272 us; speedup 1.0000x reference)
//
#include <hip/hip_runtime.h>
#include <hip/hip_cooperative_groups.h>

namespace cg = cooperative_groups;

// Problem constants
constexpr int T_ = 16;
constexpr int D_ = 192;
constexpr int H_ = 128;
constexpr int P_ = 128;
constexpr int EC_ = 32;
constexpr int S_ = T_ * D_;  // 3072
constexpr float SCALE_ = 0.17677669529663687f;  // 1/sqrt(32)

constexpr int NB = 256;  // blocks (1 per CU, cooperative co-residency)
constexpr int NT = 512;  // threads per block (8 waves)

struct MKArgs {
  const float *x, *edge_w, *W_node, *b_node, *W_edge, *b_edge, *time_enc;
  const float *Wqkv, *bqkv, *Wo, *bo, *W1, *b1, *W2, *b2;
  const float *g1, *beta1, *g2, *beta2;
  const float *Wc1, *bc1, *Wc2, *bc2, *Wd1, *bd1, *Wd2, *bd2;
  float *z, *qkvb, *attnout, *pre;
  int *adj_cnt, *adj_list;
  float *logits, *dist;
};

__device__ __forceinline__ float wave_sum64(float v) {
#pragma unroll
  for (int m = 1; m < 64; m <<= 1) v += __shfl_xor(v, m);
  return v;
}

__global__ __launch_bounds__(NT) void mega_kernel(MKArgs a) {
  cg::grid_group grid = cg::this_grid();
  // 28672 B: attn uses 4 sub-blocks x 7168 B; GEMM stages use As(4KB)+mid(16KB)
  __shared__ __align__(16) unsigned char smem[28672];
  float* As = (float*)smem;
  const int tid = threadIdx.x;
  const int bx = blockIdx.x;

  // ===== Stage 0: adjacency compaction (blocks<192, wave0) + node embedding
  if (bx < D_ && tid < 64) {
    int lane = tid, cnt = 0;
    for (int base = 0; base < D_; base += 64) {
      int j = base + lane;
      bool pred = (a.edge_w[bx * D_ + j] > 0.f) || (j == bx);
      unsigned long long mb = __ballot(pred);
      int ofs = __popcll(mb & ((1ull << lane) - 1ull));
      if (pred) a.adj_list[bx * D_ + cnt + ofs] = j;
      cnt += __popcll(mb);
    }
    if (lane == 0) a.adj_cnt[bx] = cnt;
  }
  for (int vb = bx; vb < S_ / 8; vb += NB) {
    int m0 = vb * 8;
    for (int idx = tid; idx < 1024; idx += NT) {
      int r = idx >> 7, h = idx & 127;
      int s = m0 + r, t = s / D_, d = s - t * D_;
      As[idx] = a.x[(t * H_ + h) * D_ + d];
    }
    __syncthreads();
    int rg = tid >> 7, col = tid & 127, r0 = rg * 2;
    float c0 = a.b_node[col], c1 = c0;
    for (int h = 0; h < H_; h += 4) {
      float w0 = a.W_node[(h + 0) * P_ + col], w1 = a.W_node[(h + 1) * P_ + col];
      float w2 = a.W_node[(h + 2) * P_ + col], w3 = a.W_node[(h + 3) * P_ + col];
      float4 a0 = *(const float4*)&As[r0 * 128 + h];
      float4 a1 = *(const float4*)&As[(r0 + 1) * 128 + h];
      c0 = fmaf(a0.x, w0, c0); c0 = fmaf(a0.y, w1, c0);
      c0 = fmaf(a0.z, w2, c0); c0 = fmaf(a0.w, w3, c0);
      c1 = fmaf(a1.x, w0, c1); c1 = fmaf(a1.y, w1, c1);
      c1 = fmaf(a1.z, w2, c1); c1 = fmaf(a1.w, w3, c1);
    }
    float te = a.time_enc[col];
    int s0 = m0 + r0;
    a.z[(size_t)s0 * P_ + col] = fmaxf(c0, 0.f) + te * (float)(s0 / D_);
    a.z[(size_t)(s0 + 1) * P_ + col] = fmaxf(c1, 0.f) + te * (float)((s0 + 1) / D_);
    __syncthreads();
  }
  grid.sync();

  // ===== Transformer layers
  for (int layer = 0; layer < 2; ++layer) {
    // ---- qkv = LN(z; g1,beta1) @ Wqkv + bqkv ----
    for (int vb = bx; vb < S_ / 8; vb += NB) {
      int m0 = vb * 8;
      {
        float4* As4 = (float4*)As;
        const float4* Z4 = (const float4*)(a.z + (size_t)m0 * P_);
        for (int idx = tid; idx < 256; idx += NT) As4[idx] = Z4[idx];
      }
      __syncthreads();
      {
        int wv = tid >> 6, lane = tid & 63;
        float v0 = As[wv * 128 + lane], v1 = As[wv * 128 + 64 + lane];
        float s = wave_sum64(v0 + v1);
        float mean = s * (1.f / 128.f);
        float d0 = v0 - mean, d1 = v1 - mean;
        float q = wave_sum64(d0 * d0 + d1 * d1);
        float inv = 1.f / sqrtf(q * (1.f / 128.f) + 1e-5f);
        As[wv * 128 + lane] = d0 * inv * a.g1[lane] + a.beta1[lane];
        As[wv * 128 + 64 + lane] = d1 * inv * a.g1[lane + 64] + a.beta1[lane + 64];
      }
      __syncthreads();
      if (tid < 384) {
        int col = tid;
        float acc[8];
#pragma unroll
        for (int r = 0; r < 8; ++r) acc[r] = a.bqkv[col];
        for (int k = 0; k < 128; k += 4) {
          float b0 = a.Wqkv[(k + 0) * 384 + col], b1 = a.Wqkv[(k + 1) * 384 + col];
          float b2 = a.Wqkv[(k + 2) * 384 + col], b3 = a.Wqkv[(k + 3) * 384 + col];
#pragma unroll
          for (int r = 0; r < 8; ++r) {
            float4 av = *(const float4*)&As[r * 128 + k];
            acc[r] = fmaf(av.x, b0, acc[r]); acc[r] = fmaf(av.y, b1, acc[r]);
            acc[r] = fmaf(av.z, b2, acc[r]); acc[r] = fmaf(av.w, b3, acc[r]);
          }
        }
#pragma unroll
        for (int r = 0; r < 8; ++r) a.qkvb[(size_t)(m0 + r) * 384 + col] = acc[r];
      }
      __syncthreads();
    }
    grid.sync();

    // ---- sparse masked attention: 4 queries per block-iteration ----
    {
      int sub = tid >> 7, stid = tid & 127;
      int* klist = (int*)(smem + sub * 7168);
      float* scores = (float*)(smem + sub * 7168 + 768);
      int h = stid >> 5, dd = stid & 31;
      for (int qb = 0; qb < S_ / (NB * 4); ++qb) {  // 3 iterations
        int s = qb * NB * 4 + bx * 4 + sub;
        int t = s / D_, d1 = s - t * D_;
        int nd2 = a.adj_cnt[d1];
        for (int kd = stid; kd < nd2; kd += 128)
          klist[kd] = a.adj_list[d1 * D_ + kd];
        __syncthreads();
        int t0 = (t > 0) ? t - 1 : 0;
        int ntp = (t > 0) ? 2 : 1;
        int nk = nd2 * ntp;
        float q = a.qkvb[(size_t)s * 384 + stid];
        for (int tp = 0; tp < ntp; ++tp) {
          int tt = t0 + tp;
          for (int kd = 0; kd < nd2; ++kd) {
            int sk = tt * D_ + klist[kd];
            float partial = q * a.qkvb[(size_t)sk * 384 + P_ + stid];
            partial += __shfl_xor(partial, 1);
            partial += __shfl_xor(partial, 2);
            partial += __shfl_xor(partial, 4);
            partial += __shfl_xor(partial, 8);
            partial += __shfl_xor(partial, 16);
            if (dd == 0) scores[h * 384 + tp * nd2 + kd] = partial * SCALE_;
          }
        }
        // softmax within each 32-lane head group (same wave wrote scores[h])
        float mx = -1e30f;
        for (int ki = dd; ki < nk; ki += 32) mx = fmaxf(mx, scores[h * 384 + ki]);
        mx = fmaxf(mx, __shfl_xor(mx, 1));
        mx = fmaxf(mx, __shfl_xor(mx, 2));
        mx = fmaxf(mx, __shfl_xor(mx, 4));
        mx = fmaxf(mx, __shfl_xor(mx, 8));
        mx = fmaxf(mx, __shfl_xor(mx, 16));
        float ssum = 0.f;
        for (int ki = dd; ki < nk; ki += 32) {
          float e = expf(scores[h * 384 + ki] - mx);
          scores[h * 384 + ki] = e;
          ssum += e;
        }
        ssum += __shfl_xor(ssum, 1);
        ssum += __shfl_xor(ssum, 2);
        ssum += __shfl_xor(ssum, 4);
        ssum += __shfl_xor(ssum, 8);
        ssum += __shfl_xor(ssum, 16);
        float inv = 1.f / ssum;
        float acc = 0.f;
        for (int tp = 0; tp < ntp; ++tp) {
          int tt = t0 + tp;
          for (int kd = 0; kd < nd2; ++kd) {
            float aev = scores[h * 384 + tp * nd2 + kd];
            int sk = tt * D_ + klist[kd];
            acc = fmaf(aev, a.qkvb[(size_t)sk * 384 + 2 * P_ + stid], acc);
          }
        }
        a.attnout[(size_t)s * P_ + stid] = acc * inv;
        __syncthreads();
      }
    }
    grid.sync();

    // ---- z += attnout @ Wo + bo ----
    for (int vb = bx; vb < S_ / 8; vb += NB) {
      int m0 = vb * 8;
      {
        float4* As4 = (float4*)As;
        const float4* A4 = (const float4*)(a.attnout + (size_t)m0 * P_);
        for (int idx = tid; idx < 256; idx += NT) As4[idx] = A4[idx];
      }
      __syncthreads();
      int rg = tid >> 7, col = tid & 127, r0 = rg * 2;
      float c0 = 0.f, c1 = 0.f;
      for (int k = 0; k < 128; k += 4) {
        float w0 = a.Wo[(k + 0) * P_ + col], w1 = a.Wo[(k + 1) * P_ + col];
        float w2 = a.Wo[(k + 2) * P_ + col], w3 = a.Wo[(k + 3) * P_ + col];
        float4 a0 = *(const float4*)&As[r0 * 128 + k];
        float4 a1 = *(const float4*)&As[(r0 + 1) * 128 + k];
        c0 = fmaf(a0.x, w0, c0); c0 = fmaf(a0.y, w1, c0);
        c0 = fmaf(a0.z, w2, c0); c0 = fmaf(a0.w, w3, c0);
        c1 = fmaf(a1.x, w0, c1); c1 = fmaf(a1.y, w1, c1);
        c1 = fmaf(a1.z, w2, c1); c1 = fmaf(a1.w, w3, c1);
      }
      float bb = a.bo[col];
      a.z[(size_t)(m0 + r0) * P_ + col] += c0 + bb;
      a.z[(size_t)(m0 + r0 + 1) * P_ + col] += c1 + bb;
      __syncthreads();
    }
    grid.sync();

    // ---- z += relu(LN(z; g2,beta2) @ W1 + b1) @ W2 + b2 (FF fused via LDS) ----
    for (int vb = bx; vb < S_ / 8; vb += NB) {
      int m0 = vb * 8;
      float* mid = (float*)(smem + 4096);  // [8][512]
      {
        float4* As4 = (float4*)As;
        const float4* Z4 = (const float4*)(a.z + (size_t)m0 * P_);
        for (int idx = tid; idx < 256; idx += NT) As4[idx] = Z4[idx];
      }
      __syncthreads();
      {
        int wv = tid >> 6, lane = tid & 63;
        float v0 = As[wv * 128 + lane], v1 = As[wv * 128 + 64 + lane];
        float s = wave_sum64(v0 + v1);
        float mean = s * (1.f / 128.f);
        float d0 = v0 - mean, d1 = v1 - mean;
        float q = wave_sum64(d0 * d0 + d1 * d1);
        float inv = 1.f / sqrtf(q * (1.f / 128.f) + 1e-5f);
        As[wv * 128 + lane] = d0 * inv * a.g2[lane] + a.beta2[lane];
        As[wv * 128 + 64 + lane] = d1 * inv * a.g2[lane + 64] + a.beta2[lane + 64];
      }
      __syncthreads();
      {  // FF1: all 512 cols
        int col = tid;
        float acc[8];
#pragma unroll
        for (int r = 0; r < 8; ++r) acc[r] = a.b1[col];
        for (int k = 0; k < 128; k += 4) {
          float b0 = a.W1[(k + 0) * 512 + col], b1 = a.W1[(k + 1) * 512 + col];
          float b2 = a.W1[(k + 2) * 512 + col], b3 = a.W1[(k + 3) * 512 + col];
#pragma unroll
          for (int r = 0; r < 8; ++r) {
            float4 av = *(const float4*)&As[r * 128 + k];
            acc[r] = fmaf(av.x, b0, acc[r]); acc[r] = fmaf(av.y, b1, acc[r]);
            acc[r] = fmaf(av.z, b2, acc[r]); acc[r] = fmaf(av.w, b3, acc[r]);
          }
        }
#pragma unroll
        for (int r = 0; r < 8; ++r) mid[r * 512 + col] = fmaxf(acc[r], 0.f);
      }
      __syncthreads();
      {  // FF2: 4 rowgroups x 128 cols, K=512 from LDS
        int rg = tid >> 7, col = tid & 127, r0 = rg * 2;
        float c0 = 0.f, c1 = 0.f;
        for (int k = 0; k < 512; k += 4) {
          float w0 = a.W2[(k + 0) * P_ + col], w1 = a.W2[(k + 1) * P_ + col];
          float w2 = a.W2[(k + 2) * P_ + col], w3 = a.W2[(k + 3) * P_ + col];
          float4 a0 = *(const float4*)&mid[r0 * 512 + k];
          float4 a1 = *(const float4*)&mid[(r0 + 1) * 512 + k];
          c0 = fmaf(a0.x, w0, c0); c0 = fmaf(a0.y, w1, c0);
          c0 = fmaf(a0.z, w2, c0); c0 = fmaf(a0.w, w3, c0);
          c1 = fmaf(a1.x, w0, c1); c1 = fmaf(a1.y, w1, c1);
          c1 = fmaf(a1.z, w2, c1); c1 = fmaf(a1.w, w3, c1);
        }
        float bb = a.b2[col];
        a.z[(size_t)(m0 + r0) * P_ + col] += c0 + bb;
        a.z[(size_t)(m0 + r0 + 1) * P_ + col] += c1 + bb;
      }
      __syncthreads();
    }
    grid.sync();
  }

  // ===== pre = z @ [Wc1[:P] | Wc1[P:2P] | Wd1[:P] | Wd1[P:]] (segmented N=512)
  for (int vb = bx; vb < S_ / 8; vb += NB) {
    int m0 = vb * 8;
    {
      float4* As4 = (float4*)As;
      const float4* Z4 = (const float4*)(a.z + (size_t)m0 * P_);
      for (int idx = tid; idx < 256; idx += NT) As4[idx] = Z4[idx];
    }
    __syncthreads();
    int col = tid;
    int seg = col >> 7, cc = col & 127;
    const float* Bbase = (seg < 2 ? a.Wc1 : a.Wd1) + ((seg & 1) ? P_ * P_ : 0) + cc;
    float acc[8];
#pragma unroll
    for (int r = 0; r < 8; ++r) acc[r] = 0.f;
    for (int k = 0; k < 128; k += 4) {
      float b0 = Bbase[(size_t)(k + 0) * P_], b1 = Bbase[(size_t)(k + 1) * P_];
      float b2 = Bbase[(size_t)(k + 2) * P_], b3 = Bbase[(size_t)(k + 3) * P_];
#pragma unroll
      for (int r = 0; r < 8; ++r) {
        float4 av = *(const float4*)&As[r * 128 + k];
        acc[r] = fmaf(av.x, b0, acc[r]); acc[r] = fmaf(av.y, b1, acc[r]);
        acc[r] = fmaf(av.z, b2, acc[r]); acc[r] = fmaf(av.w, b3, acc[r]);
      }
    }
#pragma unroll
    for (int r = 0; r < 8; ++r) a.pre[(size_t)(m0 + r) * 512 + col] = acc[r];
    __syncthreads();
  }
  grid.sync();

  // ===== logits (active entries only; full -1e9 row fill) + dist, wave per item
  {
    int gwid = bx * 8 + (tid >> 6);
    int lane = tid & 63;
    for (int w = gwid; w < (T_ - 1) * D_; w += NB * 8) {
      int t = w / D_, i = w - t * D_;
      float* lrow = a.logits + (size_t)w * D_;
      for (int j = lane; j < D_; j += 64) lrow[j] = -1e9f;
      const float* hnr = a.pre + (size_t)((t + 1) * D_ + i) * 512;
      float hn0 = hnr[lane], hn1 = hnr[lane + 64];
      float bc1_0 = a.bc1[lane], bc1_1 = a.bc1[lane + 64];
      float wc0 = a.Wc2[lane], wc1 = a.Wc2[lane + 64];
      float bb = a.bc2[0];
      const float* Wc1e = a.Wc1 + 2 * P_ * P_;
      int cnt = a.adj_cnt[i];
      for (int jj = 0; jj < cnt; ++jj) {
        int j = a.adj_list[i * D_ + jj];
        float wv = a.edge_w[i * D_ + j];
        float he0 = 0.f, he1 = 0.f;
#pragma unroll 8
        for (int e = 0; e < EC_; ++e) {
          float enc = fmaxf(fmaf(wv, a.W_edge[e], a.b_edge[e]), 0.f);
          he0 = fmaf(enc, Wc1e[e * P_ + lane], he0);
          he1 = fmaf(enc, Wc1e[e * P_ + lane + 64], he1);
        }
        const float* hcr = a.pre + (size_t)(t * D_ + j) * 512 + 128;
        float sacc = fmaxf(hn0 + hcr[lane] + he0 + bc1_0, 0.f) * wc0 +
                     fmaxf(hn1 + hcr[lane + 64] + he1 + bc1_1, 0.f) * wc1;
        sacc = wave_sum64(sacc);
        if (lane == 0) lrow[j] = sacc + bb;
      }
    }
    for (int w = gwid; w < (T_ - 1) * D_; w += NB * 8) {
      const float* ar = a.pre + (size_t)w * 512 + 256;
      const float* br = a.pre + (size_t)(w + D_) * 512 + 384;
      float v0 = fmaxf(ar[lane] + br[lane] + a.bd1[lane], 0.f) * a.Wd2[lane];
      float v1 = fmaxf(ar[lane + 64] + br[lane + 64] + a.bd1[lane + 64], 0.f) * a.Wd2[lane + 64];
      float s = wave_sum64(v0 + v1);
      if (lane == 0) a.dist[w] = s + a.bd2[0];
    }
  }
}

// ---------------------------------------------------------------------------
extern "C" void kernel_launch(void* const* d_in, const int* in_sizes, int n_in,
                              void* d_out, int out_size, void* d_ws,
                              size_t ws_size, hipStream_t stream) {
  MKArgs a;
  a.x = (const float*)d_in[0];
  a.edge_w = (const float*)d_in[1];
  a.W_node = (const float*)d_in[2];
  a.b_node = (const float*)d_in[3];
  a.W_edge = (const float*)d_in[4];
  a.b_edge = (const float*)d_in[5];
  a.time_enc = (const float*)d_in[6];
  a.Wqkv = (const float*)d_in[7];
  a.bqkv = (const float*)d_in[8];
  a.Wo = (const float*)d_in[9];
  a.bo = (const float*)d_in[10];
  a.W1 = (const float*)d_in[11];
  a.b1 = (const float*)d_in[12];
  a.W2 = (const float*)d_in[13];
  a.b2 = (const float*)d_in[14];
  a.g1 = (const float*)d_in[15];
  a.beta1 = (const float*)d_in[16];
  a.g2 = (const float*)d_in[17];
  a.beta2 = (const float*)d_in[18];
  a.Wc1 = (const float*)d_in[19];
  a.bc1 = (const float*)d_in[20];
  a.Wc2 = (const float*)d_in[21];
  a.bc2 = (const float*)d_in[22];
  a.Wd1 = (const float*)d_in[23];
  a.bd1 = (const float*)d_in[24];
  a.Wd2 = (const float*)d_in[25];
  a.bd2 = (const float*)d_in[26];

  float* ws = (float*)d_ws;
  a.z = ws;                        // S*128
  a.qkvb = a.z + S_ * 128;         // S*384
  a.attnout = a.qkvb + S_ * 384;   // S*128
  a.pre = a.attnout + S_ * 128;    // S*512
  a.adj_cnt = (int*)(a.pre + S_ * 512);  // D_
  a.adj_list = a.adj_cnt + D_;           // D_*D_

  a.logits = (float*)d_out;
  a.dist = (float*)d_out + (T_ - 1) * D_ * D_;

  void* kargs[] = {&a};
  hipLaunchCooperativeKernel((const void*)mega_kernel, dim3(NB), dim3(NT),
                             kargs, 0, stream);
}

// Round 7
// 326.143 us; speedup vs baseline: 2.3955x; 2.3955x over previous
//
#include <hip/hip_runtime.h>

// Problem constants
constexpr int T_ = 16;
constexpr int D_ = 192;
constexpr int H_ = 128;
constexpr int P_ = 128;
constexpr int EC_ = 32;
constexpr int S_ = T_ * D_;  // 3072
constexpr int FF_ = 512;
constexpr float SCALE_ = 0.17677669529663687f;  // 1/sqrt(32)

__device__ __forceinline__ float wave_sum64(float v) {
#pragma unroll
  for (int m = 1; m < 64; m <<= 1) v += __shfl_xor(v, m);
  return v;
}

// ---------------------------------------------------------------------------
// Embed (+ adjacency compaction on blocks < D_, wave 0).
// z[s][p] = relu(sum_h x[t][h][d]*W_node[h][p] + b_node[p]) + time_enc[p]*t
// ---------------------------------------------------------------------------
__global__ __launch_bounds__(128) void embed_adj_kernel(
    const float* __restrict__ x, const float* __restrict__ W_node,
    const float* __restrict__ b_node, const float* __restrict__ time_enc,
    const float* __restrict__ edge_w, float* __restrict__ z,
    int* __restrict__ adj_cnt, int* __restrict__ adj_list) {
  int bx = blockIdx.x;
  int tid = threadIdx.x;
  if (bx < D_ && tid < 64) {  // adjacency row bx
    int lane = tid, cnt = 0;
    for (int base = 0; base < D_; base += 64) {
      int j = base + lane;
      bool pred = (edge_w[bx * D_ + j] > 0.f) || (j == bx);
      unsigned long long mb = __ballot(pred);
      int ofs = __popcll(mb & ((1ull << lane) - 1ull));
      if (pred) adj_list[bx * D_ + cnt + ofs] = j;
      cnt += __popcll(mb);
    }
    if (lane == 0) adj_cnt[bx] = cnt;
  }
  __shared__ float As[8 * H_];
  int m0 = bx * 8;
  for (int idx = tid; idx < 8 * H_; idx += 128) {
    int r = idx >> 7, h = idx & 127;
    int s = m0 + r, t = s / D_, d = s - t * D_;
    As[idx] = x[(t * H_ + h) * D_ + d];
  }
  __syncthreads();
  int j = tid;
  float acc[8];
  float bj = b_node[j];
#pragma unroll
  for (int r = 0; r < 8; ++r) acc[r] = bj;
  for (int h = 0; h < H_; h += 4) {
    float w0 = W_node[(h + 0) * P_ + j], w1 = W_node[(h + 1) * P_ + j];
    float w2 = W_node[(h + 2) * P_ + j], w3 = W_node[(h + 3) * P_ + j];
#pragma unroll
    for (int r = 0; r < 8; ++r) {
      const float4 a = *reinterpret_cast<const float4*>(&As[r * H_ + h]);
      acc[r] = fmaf(a.x, w0, acc[r]);
      acc[r] = fmaf(a.y, w1, acc[r]);
      acc[r] = fmaf(a.z, w2, acc[r]);
      acc[r] = fmaf(a.w, w3, acc[r]);
    }
  }
  float te = time_enc[j];
#pragma unroll
  for (int r = 0; r < 8; ++r) {
    int s = m0 + r;
    z[(size_t)s * P_ + j] = fmaxf(acc[r], 0.f) + te * (float)(s / D_);
  }
}

// ---------------------------------------------------------------------------
// qkv = LN(z; g1,beta1) @ Wqkv + bqkv.  BM=16 rows, NT=192, CPT=2.
// ---------------------------------------------------------------------------
__global__ __launch_bounds__(192) void qkv_kernel(
    const float* __restrict__ z, const float* __restrict__ Wqkv,
    const float* __restrict__ bqkv, const float* __restrict__ g,
    const float* __restrict__ b, float* __restrict__ qkvb) {
  constexpr int BM = 16, NT = 192, N = 384;
  int m0 = blockIdx.x * BM;
  int tid = threadIdx.x;
  __shared__ float As[BM * 128];
  {
    float4* As4 = (float4*)As;
    const float4* Z4 = (const float4*)(z + (size_t)m0 * 128);
    for (int idx = tid; idx < BM * 32; idx += NT) As4[idx] = Z4[idx];
  }
  __syncthreads();
  {
    int wv = tid >> 6, lane = tid & 63;
    for (int r = wv; r < BM; r += 3) {
      float v0 = As[r * 128 + lane], v1 = As[r * 128 + 64 + lane];
      float s = wave_sum64(v0 + v1);
      float mean = s * (1.f / 128.f);
      float d0 = v0 - mean, d1 = v1 - mean;
      float q = wave_sum64(d0 * d0 + d1 * d1);
      float inv = 1.f / sqrtf(q * (1.f / 128.f) + 1e-5f);
      As[r * 128 + lane] = d0 * inv * g[lane] + b[lane];
      As[r * 128 + 64 + lane] = d1 * inv * g[lane + 64] + b[lane + 64];
    }
  }
  __syncthreads();
  int c0 = 2 * tid;
  float acc0[BM], acc1[BM];
  float b0c = bqkv[c0], b1c = bqkv[c0 + 1];
#pragma unroll
  for (int r = 0; r < BM; ++r) {
    acc0[r] = b0c;
    acc1[r] = b1c;
  }
  for (int k = 0; k < 128; k += 4) {
    float2 bv0 = *(const float2*)(Wqkv + (size_t)(k + 0) * N + c0);
    float2 bv1 = *(const float2*)(Wqkv + (size_t)(k + 1) * N + c0);
    float2 bv2 = *(const float2*)(Wqkv + (size_t)(k + 2) * N + c0);
    float2 bv3 = *(const float2*)(Wqkv + (size_t)(k + 3) * N + c0);
#pragma unroll
    for (int r = 0; r < BM; ++r) {
      const float4 a = *(const float4*)&As[r * 128 + k];
      acc0[r] = fmaf(a.x, bv0.x, acc0[r]);
      acc1[r] = fmaf(a.x, bv0.y, acc1[r]);
      acc0[r] = fmaf(a.y, bv1.x, acc0[r]);
      acc1[r] = fmaf(a.y, bv1.y, acc1[r]);
      acc0[r] = fmaf(a.z, bv2.x, acc0[r]);
      acc1[r] = fmaf(a.z, bv2.y, acc1[r]);
      acc0[r] = fmaf(a.w, bv3.x, acc0[r]);
      acc1[r] = fmaf(a.w, bv3.y, acc1[r]);
    }
  }
#pragma unroll
  for (int r = 0; r < BM; ++r) {
    float2 nv;
    nv.x = acc0[r];
    nv.y = acc1[r];
    *(float2*)(qkvb + (size_t)(m0 + r) * N + c0) = nv;
  }
}

// ---------------------------------------------------------------------------
// Sparse attention + Wo projection + residual. One block (128 thr) per query.
// z[s] += softmax(QK^T masked) V @ Wo + bo
// ---------------------------------------------------------------------------
__global__ __launch_bounds__(128) void attn_wo_kernel(
    const float* __restrict__ qkvb, const int* __restrict__ adj_cnt,
    const int* __restrict__ adj_list, const float* __restrict__ Wo,
    const float* __restrict__ bo, float* __restrict__ z) {
  int s = blockIdx.x;
  int t = s / D_, d1 = s - t * D_;
  int tid = threadIdx.x;
  __shared__ int klist[D_];
  __shared__ float scores[4][2 * D_];
  __shared__ float att[128];

  int nd2 = adj_cnt[d1];
  for (int kd = tid; kd < nd2; kd += 128) klist[kd] = adj_list[d1 * D_ + kd];
  __syncthreads();
  int t0 = (t > 0) ? t - 1 : 0;
  int ntp = (t > 0) ? 2 : 1;
  int nk = nd2 * ntp;

  float q = qkvb[(size_t)s * 384 + tid];
  int h = tid >> 5, dd = tid & 31;

  for (int tp = 0; tp < ntp; ++tp) {
    int tt = t0 + tp;
    for (int kd = 0; kd < nd2; ++kd) {
      int sk = tt * D_ + klist[kd];
      float partial = q * qkvb[(size_t)sk * 384 + P_ + tid];
      partial += __shfl_xor(partial, 1);
      partial += __shfl_xor(partial, 2);
      partial += __shfl_xor(partial, 4);
      partial += __shfl_xor(partial, 8);
      partial += __shfl_xor(partial, 16);
      if (dd == 0) scores[h][tp * nd2 + kd] = partial * SCALE_;
    }
  }
  // same-wave LDS visibility: head h's scores were written by this wave
  float mx = -1e30f;
  for (int ki = dd; ki < nk; ki += 32) mx = fmaxf(mx, scores[h][ki]);
  mx = fmaxf(mx, __shfl_xor(mx, 1));
  mx = fmaxf(mx, __shfl_xor(mx, 2));
  mx = fmaxf(mx, __shfl_xor(mx, 4));
  mx = fmaxf(mx, __shfl_xor(mx, 8));
  mx = fmaxf(mx, __shfl_xor(mx, 16));
  float ssum = 0.f;
  for (int ki = dd; ki < nk; ki += 32) {
    float e = expf(scores[h][ki] - mx);
    scores[h][ki] = e;
    ssum += e;
  }
  ssum += __shfl_xor(ssum, 1);
  ssum += __shfl_xor(ssum, 2);
  ssum += __shfl_xor(ssum, 4);
  ssum += __shfl_xor(ssum, 8);
  ssum += __shfl_xor(ssum, 16);
  float inv = 1.f / ssum;

  float acc = 0.f;
  for (int tp = 0; tp < ntp; ++tp) {
    int tt = t0 + tp;
    for (int kd = 0; kd < nd2; ++kd) {
      float aev = scores[h][tp * nd2 + kd];
      int sk = tt * D_ + klist[kd];
      acc = fmaf(aev, qkvb[(size_t)sk * 384 + 2 * P_ + tid], acc);
    }
  }
  att[tid] = acc * inv;
  __syncthreads();

  // Wo projection: z[s][c] += sum_k att[k]*Wo[k][c] + bo[c]
  int c = tid;
  float p = 0.f;
  for (int k = 0; k < 128; k += 4) {
    const float4 a = *(const float4*)&att[k];
    p = fmaf(a.x, Wo[(size_t)(k + 0) * P_ + c], p);
    p = fmaf(a.y, Wo[(size_t)(k + 1) * P_ + c], p);
    p = fmaf(a.z, Wo[(size_t)(k + 2) * P_ + c], p);
    p = fmaf(a.w, Wo[(size_t)(k + 3) * P_ + c], p);
  }
  z[(size_t)s * P_ + c] += p + bo[c];
}

// ---------------------------------------------------------------------------
// Fused FFN: z += relu(LN(z;g2,beta2) @ W1 + b1) @ W2 + b2.
// BM=8 rows, NT=256. mid kept in LDS (8x512).
// ---------------------------------------------------------------------------
__global__ __launch_bounds__(256) void ffn_kernel(
    const float* __restrict__ zin, const float* __restrict__ W1,
    const float* __restrict__ b1, const float* __restrict__ W2,
    const float* __restrict__ b2, const float* __restrict__ g,
    const float* __restrict__ b, float* __restrict__ z) {
  constexpr int BM = 8, NT = 256;
  int m0 = blockIdx.x * BM;
  int tid = threadIdx.x;
  __shared__ float As[BM * 128];
  __shared__ float mid[BM * FF_];
  {
    float4* As4 = (float4*)As;
    const float4* Z4 = (const float4*)(zin + (size_t)m0 * 128);
    for (int idx = tid; idx < BM * 32; idx += NT) As4[idx] = Z4[idx];
  }
  __syncthreads();
  {
    int wv = tid >> 6, lane = tid & 63;
    for (int r = wv; r < BM; r += 4) {
      float v0 = As[r * 128 + lane], v1 = As[r * 128 + 64 + lane];
      float s = wave_sum64(v0 + v1);
      float mean = s * (1.f / 128.f);
      float d0 = v0 - mean, d1 = v1 - mean;
      float qv = wave_sum64(d0 * d0 + d1 * d1);
      float inv = 1.f / sqrtf(qv * (1.f / 128.f) + 1e-5f);
      As[r * 128 + lane] = d0 * inv * g[lane] + b[lane];
      As[r * 128 + 64 + lane] = d1 * inv * g[lane + 64] + b[lane + 64];
    }
  }
  __syncthreads();
  {  // FF1: CPT=2, cols c0,c0+1
    int c0 = 2 * tid;
    float acc0[BM], acc1[BM];
    float bb0 = b1[c0], bb1 = b1[c0 + 1];
#pragma unroll
    for (int r = 0; r < BM; ++r) {
      acc0[r] = bb0;
      acc1[r] = bb1;
    }
    for (int k = 0; k < 128; k += 4) {
      float2 bv0 = *(const float2*)(W1 + (size_t)(k + 0) * FF_ + c0);
      float2 bv1 = *(const float2*)(W1 + (size_t)(k + 1) * FF_ + c0);
      float2 bv2 = *(const float2*)(W1 + (size_t)(k + 2) * FF_ + c0);
      float2 bv3 = *(const float2*)(W1 + (size_t)(k + 3) * FF_ + c0);
#pragma unroll
      for (int r = 0; r < BM; ++r) {
        const float4 a = *(const float4*)&As[r * 128 + k];
        acc0[r] = fmaf(a.x, bv0.x, acc0[r]);
        acc1[r] = fmaf(a.x, bv0.y, acc1[r]);
        acc0[r] = fmaf(a.y, bv1.x, acc0[r]);
        acc1[r] = fmaf(a.y, bv1.y, acc1[r]);
        acc0[r] = fmaf(a.z, bv2.x, acc0[r]);
        acc1[r] = fmaf(a.z, bv2.y, acc1[r]);
        acc0[r] = fmaf(a.w, bv3.x, acc0[r]);
        acc1[r] = fmaf(a.w, bv3.y, acc1[r]);
      }
    }
#pragma unroll
    for (int r = 0; r < BM; ++r) {
      mid[r * FF_ + c0] = fmaxf(acc0[r], 0.f);
      mid[r * FF_ + c0 + 1] = fmaxf(acc1[r], 0.f);
    }
  }
  __syncthreads();
  {  // FF2: 2 rowgroups x 128 cols, 4 rows each, K=512 from LDS
    int rg = tid >> 7, col = tid & 127;
    int r0 = rg * 4;
    float acc[4] = {0.f, 0.f, 0.f, 0.f};
    for (int k = 0; k < FF_; k += 4) {
      float w0 = W2[(size_t)(k + 0) * P_ + col];
      float w1 = W2[(size_t)(k + 1) * P_ + col];
      float w2 = W2[(size_t)(k + 2) * P_ + col];
      float w3 = W2[(size_t)(k + 3) * P_ + col];
#pragma unroll
      for (int i = 0; i < 4; ++i) {
        const float4 a = *(const float4*)&mid[(r0 + i) * FF_ + k];
        acc[i] = fmaf(a.x, w0, acc[i]);
        acc[i] = fmaf(a.y, w1, acc[i]);
        acc[i] = fmaf(a.z, w2, acc[i]);
        acc[i] = fmaf(a.w, w3, acc[i]);
      }
    }
    float bb = b2[col];
#pragma unroll
    for (int i = 0; i < 4; ++i)
      z[(size_t)(m0 + r0 + i) * P_ + col] += acc[i] + bb;
  }
}

// ---------------------------------------------------------------------------
// pre = z @ [Wc1[:P] | Wc1[P:2P] | Wd1[:P] | Wd1[P:]]  (N=512 segmented)
// ---------------------------------------------------------------------------
__global__ __launch_bounds__(256) void pre_gemm_kernel(
    const float* __restrict__ A, const float* __restrict__ Wc1,
    const float* __restrict__ Wd1, float* __restrict__ pre) {
  constexpr int K = 128, N = 512, NT = 256, BM = 8;
  int m0 = blockIdx.x * BM;
  int tid = threadIdx.x;
  __shared__ float As[BM * K];
  {
    float4* As4 = (float4*)As;
    const float4* A4 = (const float4*)(A + (size_t)m0 * K);
    for (int idx = tid; idx < BM * K / 4; idx += NT) As4[idx] = A4[idx];
  }
  __syncthreads();
  int c0 = 2 * tid;
  int seg = c0 >> 7, cc = c0 & 127;
  const float* Bbase = (seg < 2 ? Wc1 : Wd1) + ((seg & 1) ? P_ * P_ : 0) + cc;
  float acc0[BM], acc1[BM];
#pragma unroll
  for (int r = 0; r < BM; ++r) {
    acc0[r] = 0.f;
    acc1[r] = 0.f;
  }
  for (int k = 0; k < K; k += 4) {
    float2 bv0 = *(const float2*)(Bbase + (size_t)(k + 0) * P_);
    float2 bv1 = *(const float2*)(Bbase + (size_t)(k + 1) * P_);
    float2 bv2 = *(const float2*)(Bbase + (size_t)(k + 2) * P_);
    float2 bv3 = *(const float2*)(Bbase + (size_t)(k + 3) * P_);
#pragma unroll
    for (int r = 0; r < BM; ++r) {
      const float4 a = *(const float4*)&As[r * K + k];
      acc0[r] = fmaf(a.x, bv0.x, acc0[r]);
      acc1[r] = fmaf(a.x, bv0.y, acc1[r]);
      acc0[r] = fmaf(a.y, bv1.x, acc0[r]);
      acc1[r] = fmaf(a.y, bv1.y, acc1[r]);
      acc0[r] = fmaf(a.z, bv2.x, acc0[r]);
      acc1[r] = fmaf(a.z, bv2.y, acc1[r]);
      acc0[r] = fmaf(a.w, bv3.x, acc0[r]);
      acc1[r] = fmaf(a.w, bv3.y, acc1[r]);
    }
  }
#pragma unroll
  for (int r = 0; r < BM; ++r) {
    float2 nv;
    nv.x = acc0[r];
    nv.y = acc1[r];
    *(float2*)(pre + (size_t)(m0 + r) * N + c0) = nv;
  }
}

// ---------------------------------------------------------------------------
// Logits (active entries; full -1e9 fill) + dist epilogue. grid (D_, T_-1).
// ---------------------------------------------------------------------------
__global__ __launch_bounds__(64) void logits_dist_kernel(
    const float* __restrict__ pre, const int* __restrict__ adj_cnt,
    const int* __restrict__ adj_list, const float* __restrict__ edge_w,
    const float* __restrict__ W_edge, const float* __restrict__ b_edge,
    const float* __restrict__ Wc1e, const float* __restrict__ bc1,
    const float* __restrict__ Wc2, const float* __restrict__ bc2,
    const float* __restrict__ bd1, const float* __restrict__ Wd2,
    const float* __restrict__ bd2, float* __restrict__ logits,
    float* __restrict__ dist) {
  int i = blockIdx.x;
  int t = blockIdx.y;
  int lane = threadIdx.x;
  int w = t * D_ + i;
  float* lrow = logits + (size_t)w * D_;
  for (int j = lane; j < D_; j += 64) lrow[j] = -1e9f;

  const float* hnr = pre + (size_t)((t + 1) * D_ + i) * 512;
  float hn0 = hnr[lane], hn1 = hnr[lane + 64];
  float bc1_0 = bc1[lane], bc1_1 = bc1[lane + 64];
  float wc0 = Wc2[lane], wc1 = Wc2[lane + 64];
  float bb = bc2[0];
  int cnt = adj_cnt[i];
  for (int jj = 0; jj < cnt; ++jj) {
    int j = adj_list[i * D_ + jj];
    float wv = edge_w[i * D_ + j];
    float he0 = 0.f, he1 = 0.f;
#pragma unroll 8
    for (int e = 0; e < EC_; ++e) {
      float enc = fmaxf(fmaf(wv, W_edge[e], b_edge[e]), 0.f);
      he0 = fmaf(enc, Wc1e[e * P_ + lane], he0);
      he1 = fmaf(enc, Wc1e[e * P_ + lane + 64], he1);
    }
    const float* hcr = pre + (size_t)(t * D_ + j) * 512 + 128;
    float sacc = fmaxf(hn0 + hcr[lane] + he0 + bc1_0, 0.f) * wc0 +
                 fmaxf(hn1 + hcr[lane + 64] + he1 + bc1_1, 0.f) * wc1;
    sacc = wave_sum64(sacc);
    if (lane == 0) lrow[j] = sacc + bb;
  }

  // dist epilogue for row w
  const float* ar = pre + (size_t)w * 512 + 256;
  const float* br = pre + (size_t)(w + D_) * 512 + 384;
  float v0 = fmaxf(ar[lane] + br[lane] + bd1[lane], 0.f) * Wd2[lane];
  float v1 = fmaxf(ar[lane + 64] + br[lane + 64] + bd1[lane + 64], 0.f) * Wd2[lane + 64];
  float sd = wave_sum64(v0 + v1);
  if (lane == 0) dist[w] = sd + bd2[0];
}

// ---------------------------------------------------------------------------
extern "C" void kernel_launch(void* const* d_in, const int* in_sizes, int n_in,
                              void* d_out, int out_size, void* d_ws,
                              size_t ws_size, hipStream_t stream) {
  const float* x = (const float*)d_in[0];
  const float* edge_w = (const float*)d_in[1];
  const float* W_node = (const float*)d_in[2];
  const float* b_node = (const float*)d_in[3];
  const float* W_edge = (const float*)d_in[4];
  const float* b_edge = (const float*)d_in[5];
  const float* time_enc = (const float*)d_in[6];
  const float* Wqkv = (const float*)d_in[7];
  const float* bqkv = (const float*)d_in[8];
  const float* Wo = (const float*)d_in[9];
  const float* bo = (const float*)d_in[10];
  const float* W1 = (const float*)d_in[11];
  const float* b1 = (const float*)d_in[12];
  const float* W2 = (const float*)d_in[13];
  const float* b2 = (const float*)d_in[14];
  const float* g1 = (const float*)d_in[15];
  const float* beta1 = (const float*)d_in[16];
  const float* g2 = (const float*)d_in[17];
  const float* beta2 = (const float*)d_in[18];
  const float* Wc1 = (const float*)d_in[19];
  const float* bc1 = (const float*)d_in[20];
  const float* Wc2 = (const float*)d_in[21];
  const float* bc2 = (const float*)d_in[22];
  const float* Wd1 = (const float*)d_in[23];
  const float* bd1 = (const float*)d_in[24];
  const float* Wd2 = (const float*)d_in[25];
  const float* bd2 = (const float*)d_in[26];

  float* ws = (float*)d_ws;
  float* z = ws;                   // S*128
  float* qkvb = z + S_ * 128;      // S*384
  float* pre = qkvb + S_ * 384;    // S*512
  int* adj_cnt = (int*)(pre + S_ * 512);  // D_
  int* adj_list = adj_cnt + D_;           // D_*D_

  float* logits = (float*)d_out;
  float* dist = (float*)d_out + (T_ - 1) * D_ * D_;

  embed_adj_kernel<<<S_ / 8, 128, 0, stream>>>(x, W_node, b_node, time_enc,
                                               edge_w, z, adj_cnt, adj_list);
  for (int it = 0; it < 2; ++it) {
    qkv_kernel<<<S_ / 16, 192, 0, stream>>>(z, Wqkv, bqkv, g1, beta1, qkvb);
    attn_wo_kernel<<<S_, 128, 0, stream>>>(qkvb, adj_cnt, adj_list, Wo, bo, z);
    ffn_kernel<<<S_ / 8, 256, 0, stream>>>(z, W1, b1, W2, b2, g2, beta2, z);
  }
  pre_gemm_kernel<<<S_ / 8, 256, 0, stream>>>(z, Wc1, Wd1, pre);
  logits_dist_kernel<<<dim3(D_, T_ - 1), 64, 0, stream>>>(
      pre, adj_cnt, adj_list, edge_w, W_edge, b_edge, Wc1 + 2 * P_ * P_, bc1,
      Wc2, bc2, bd1, Wd2, bd2, logits, dist);
}